// Round 6
// baseline (177.966 us; speedup 1.0000x reference)
//
#include <hip/hip_runtime.h>
#include <hip/hip_bf16.h>
#include <stdint.h>

#define NJ 21
#define ROWS_TOTAL (16384*21)      /* 344064 */
#define TILE_ROWS 63               /* 3 batches per tile (one WG) */
#define NTILES ((ROWS_TOTAL + TILE_ROWS - 1)/TILE_ROWS)  /* 5462 */
#define WPG 4                      /* 4 waves per WG, each owns 32 output feats */

typedef __attribute__((ext_vector_type(8))) short short8;
typedef __attribute__((ext_vector_type(4))) float f32x4;

/* wave-local LDS fence: cross-lane visibility within one wave */
#define WAVE_SYNC() asm volatile("s_waitcnt lgkmcnt(0)" ::: "memory")

__device__ __forceinline__ uint16_t f2bf(float f){
  union{float f; uint32_t u;} v; v.f = f;
  uint32_t r = v.u + 0x7FFF + ((v.u>>16)&1);
  return (uint16_t)(r>>16);
}

/* idx<16384:  Up[frag]   = bf16( (W1@W2a)[k][n] )      (U = W1 @ W2_w[0:128])
   idx<32768:  w2bp[frag] = bf16( W2_w[128+k][n] )
   idx<34816:  stp[frag]  = B-tile [ws | wt | 0...]:  n==0 -> (W1@a1)[k], n==1 -> (W1@a2)[k]
   frag layout: buf[(tile*64 + lane)*8 + e] = M[k=32ks+8*(lane>>4)+e][n=16nt+(lane&15)] */
__global__ void pack_kernel(const float* __restrict__ W1, const float* __restrict__ W2,
                            const float* __restrict__ a,
                            uint16_t* __restrict__ Up, uint16_t* __restrict__ w2bp,
                            uint16_t* __restrict__ stp){
  int idx = blockIdx.x*256 + threadIdx.x;       /* 0..34815 */
  if (idx < 32768){
    int which = idx >> 14;
    int sub = idx & 16383;
    int e = sub & 7, lane = (sub>>3)&63, nt = (sub>>9)&7, ks = sub>>12;
    int k = 32*ks + 8*(lane>>4) + e;
    int n = 16*nt + (lane&15);
    if (which==0){
      float acc = 0.f;
      for (int p=0;p<128;++p) acc += W1[k*128+p]*W2[p*128+n];
      Up[sub] = f2bf(acc);
    } else {
      w2bp[sub] = f2bf(W2[(128+k)*128+n]);
    }
  } else if (idx < 34816){
    int sub = idx - 32768;        /* 0..2047 */
    int e = sub & 7, lane = (sub>>3)&63, ks = (sub>>9)&3;
    int k = 32*ks + 8*(lane>>4) + e;
    int l15 = lane & 15;
    float v = 0.f;
    if (l15 == 0){ for (int p=0;p<128;++p) v += W1[k*128+p]*a[p]; }
    else if (l15 == 1){ for (int p=0;p<128;++p) v += W1[k*128+p]*a[128+p]; }
    stp[sub] = f2bf(v);
  }
}

__global__ __launch_bounds__(256,4) void camgat_kernel(
    const float* __restrict__ x, const float* __restrict__ cam,
    const float* __restrict__ bias,
    const uint16_t* __restrict__ Up, const uint16_t* __restrict__ w2bp,
    const uint16_t* __restrict__ stp,
    float* __restrict__ out)
{
  __shared__ uint16_t sALPHA[64*64];     /* shared: block-diag alpha, swizzled */
  __shared__ uint16_t sUT[WPG][32*64];   /* per-wave: u^T slice [feat32][sample64], swizzled */
  __shared__ float sST[2][64];           /* s,t per row (written redundantly, same values) */

  const int tid  = threadIdx.x;
  const int wv   = tid >> 6;
  const int lane = tid & 63;
  const int g = lane >> 4;
  const int l15 = lane & 15;
  const long row_base = (long)blockIdx.x * TILE_ROWS;

  uint16_t* myUT = sUT[wv];

  /* ---- 1: BURST all 32 x float4 loads (clamped rows), then convert ---- */
  float4 xraw[4][8];
  #pragma unroll
  for (int mi=0; mi<4; ++mi){
    long grow = row_base + 16*mi + l15;
    if (grow > (long)ROWS_TOTAL-1) grow = (long)ROWS_TOTAL-1;
    const float* xrow = x + grow*128;
    #pragma unroll
    for (int ks=0; ks<4; ++ks){
      xraw[mi][2*ks]   = *(const float4*)(xrow + 32*ks + 8*g);
      xraw[mi][2*ks+1] = *(const float4*)(xrow + 32*ks + 8*g + 4);
    }
  }
  short8 xf[4][4];
  #pragma unroll
  for (int mi=0; mi<4; ++mi)
    #pragma unroll
    for (int ks=0; ks<4; ++ks){
      float4 v0 = xraw[mi][2*ks], v1 = xraw[mi][2*ks+1];
      short8 f;
      f[0]=(short)f2bf(v0.x); f[1]=(short)f2bf(v0.y); f[2]=(short)f2bf(v0.z); f[3]=(short)f2bf(v0.w);
      f[4]=(short)f2bf(v1.x); f[5]=(short)f2bf(v1.y); f[6]=(short)f2bf(v1.z); f[7]=(short)f2bf(v1.w);
      xf[mi][ks] = f;
    }

  /* ---- 2: s,t via st-MFMA (each wave, redundant -> no cross-wave dep) ---- */
  {
    short8 stf[4];
    #pragma unroll
    for (int ks=0;ks<4;++ks)
      stf[ks] = *(const short8*)(stp + (size_t)(ks*64 + lane)*8);
    f32x4 stacc[4];
    { f32x4 z; z[0]=0.f; z[1]=0.f; z[2]=0.f; z[3]=0.f;
      #pragma unroll
      for (int mi=0;mi<4;++mi) stacc[mi]=z; }
    #pragma unroll
    for (int ks=0;ks<4;++ks)
      #pragma unroll
      for (int mi=0;mi<4;++mi)
        stacc[mi] = __builtin_amdgcn_mfma_f32_16x16x32_bf16(xf[mi][ks], stf[ks], stacc[mi], 0,0,0);
    /* scatter: C layout col=l15 (0->s, 1->t), row=16mi+4g+q; all waves write same values */
    if (l15 < 2){
      #pragma unroll
      for (int mi=0;mi<4;++mi)
        #pragma unroll
        for (int q=0;q<4;++q)
          sST[l15][16*mi+4*g+q] = stacc[mi][q];
    }
  }
  WAVE_SYNC();   /* own-wave sST writes visible */

  /* ---- 3: softmax for rows 16wv..16wv+15 -> alpha rows (disjoint across waves) ---- */
  if (lane < 16){
    int r = 16*wv + lane;
    bool vrow = (r < TILE_ROWS);
    int qq = (r>=42)?2:((r>=21)?1:0);
    int base = vrow ? 21*qq : 64;
    /* zero complement (cols outside this row's window) */
    for (int c=0;c<base;++c){
      int addr = (r*128 + c*2) ^ ((r&7)<<4);
      *(uint16_t*)((char*)sALPHA + addr) = 0;
    }
    for (int c=base+21;c<64;++c){
      int addr = (r*128 + c*2) ^ ((r&7)<<4);
      *(uint16_t*)((char*)sALPHA + addr) = 0;
    }
    if (vrow){
      int i = r - base;
      float s_r = sST[0][r];
      float ev[NJ]; float m = -1e30f;
      #pragma unroll
      for (int j=0;j<NJ;++j){
        float e = s_r + sST[1][base+j];
        e = e>0.f ? e : 0.2f*e;
        ev[j]=e; m = fmaxf(m,e);
      }
      float sum=0.f;
      #pragma unroll
      for (int j=0;j<NJ;++j){ float p = __expf(ev[j]-m); ev[j]=p; sum+=p; }
      float inv = 1.f/sum;
      #pragma unroll
      for (int j=0;j<NJ;++j){
        uint16_t ab = f2bf(cam[i*NJ+j]*ev[j]*inv);
        int addr = (r*128 + (base+j)*2) ^ ((r&7)<<4);
        *(uint16_t*)((char*)sALPHA + addr) = ab;
      }
    }
  }
  __syncthreads();   /* alpha complete; read-only hereafter */

  /* ---- 4: u-slice = x @ U[:, 32wv..32wv+31]  (M64 N32 K128) ---- */
  f32x4 uacc[4][2];
  { f32x4 z; z[0]=0.f; z[1]=0.f; z[2]=0.f; z[3]=0.f;
    #pragma unroll
    for (int mi=0;mi<4;++mi){ uacc[mi][0]=z; uacc[mi][1]=z; } }
  #pragma unroll
  for (int ks=0;ks<4;++ks){
    short8 bfu[2];
    #pragma unroll
    for (int ntl=0;ntl<2;++ntl)
      bfu[ntl] = *(const short8*)(Up + (size_t)(((ks*8)+(2*wv+ntl))*64 + lane)*8);
    #pragma unroll
    for (int mi=0;mi<4;++mi)
      #pragma unroll
      for (int ntl=0;ntl<2;++ntl)
        uacc[mi][ntl] = __builtin_amdgcn_mfma_f32_16x16x32_bf16(xf[mi][ks], bfu[ntl], uacc[mi][ntl], 0,0,0);
  }

  /* ---- 5: pack u^T slice -> own LDS (swizzled) ---- */
  #pragma unroll
  for (int mi=0;mi<4;++mi)
    #pragma unroll
    for (int ntl=0;ntl<2;++ntl){
      int c = 16*ntl + l15;        /* feat_local 0..31 */
      int r0 = 16*mi + 4*g;        /* sample */
      uint32_t lo = (uint32_t)f2bf(uacc[mi][ntl][0]) | ((uint32_t)f2bf(uacc[mi][ntl][1])<<16);
      uint32_t hi = (uint32_t)f2bf(uacc[mi][ntl][2]) | ((uint32_t)f2bf(uacc[mi][ntl][3])<<16);
      int addr = (c*128 + r0*2) ^ ((c&7)<<4);
      uint2 w; w.x=lo; w.y=hi;
      *(uint2*)((char*)myUT + addr) = w;
    }

  /* ---- 6: oacc = bias + x@W2b-slice  (loads fly while uT writes drain) ---- */
  f32x4 oacc[4][2];
  #pragma unroll
  for (int ntl=0;ntl<2;++ntl){
    float b = bias[32*wv + 16*ntl + l15];
    #pragma unroll
    for (int mi=0;mi<4;++mi){ f32x4 v; v[0]=b; v[1]=b; v[2]=b; v[3]=b; oacc[mi][ntl]=v; }
  }
  #pragma unroll
  for (int ks=0;ks<4;++ks){
    short8 bfw[2];
    #pragma unroll
    for (int ntl=0;ntl<2;++ntl)
      bfw[ntl] = *(const short8*)(w2bp + (size_t)(((ks*8)+(2*wv+ntl))*64 + lane)*8);
    #pragma unroll
    for (int mi=0;mi<4;++mi)
      #pragma unroll
      for (int ntl=0;ntl<2;++ntl)
        oacc[mi][ntl] = __builtin_amdgcn_mfma_f32_16x16x32_bf16(xf[mi][ks], bfw[ntl], oacc[mi][ntl], 0,0,0);
  }

  WAVE_SYNC();   /* own uT writes visible (alpha covered by barrier) */

  /* ---- 7: oacc += alpha @ u-slice  (M64 N32 K64) ---- */
  #pragma unroll
  for (int ks2=0;ks2<2;++ks2){
    int kb = (32*ks2 + 8*g)*2;
    short8 afr[4], bfr[2];
    #pragma unroll
    for (int mi=0;mi<4;++mi){
      int i = 16*mi + l15;
      int addr = (i*128 + kb) ^ ((i&7)<<4);
      afr[mi] = *(const short8*)((char*)sALPHA + addr);
    }
    #pragma unroll
    for (int ntl=0;ntl<2;++ntl){
      int n = 16*ntl + l15;
      int addr = (n*128 + kb) ^ ((n&7)<<4);
      bfr[ntl] = *(const short8*)((char*)myUT + addr);
    }
    #pragma unroll
    for (int mi=0;mi<4;++mi)
      #pragma unroll
      for (int ntl=0;ntl<2;++ntl)
        oacc[mi][ntl] = __builtin_amdgcn_mfma_f32_16x16x32_bf16(afr[mi], bfr[ntl], oacc[mi][ntl], 0,0,0);
  }

  /* ---- 8: ELU + predicated store of this wave's 32-col slice ---- */
  #pragma unroll
  for (int mi=0;mi<4;++mi){
    #pragma unroll
    for (int q=0;q<4;++q){
      int r = 16*mi + 4*g + q;
      long grow = row_base + r;
      if (r < TILE_ROWS && grow < (long)ROWS_TOTAL){
        float* orow = out + grow*128 + 32*wv;
        #pragma unroll
        for (int ntl=0;ntl<2;++ntl){
          float v = oacc[mi][ntl][q];
          v = v > 0.f ? v : (__expf(v) - 1.f);
          orow[16*ntl + l15] = v;
        }
      }
    }
  }
}

extern "C" void kernel_launch(void* const* d_in, const int* in_sizes, int n_in,
                              void* d_out, int out_size, void* d_ws, size_t ws_size,
                              hipStream_t stream) {
  const float* x   = (const float*)d_in[0];
  const float* cam = (const float*)d_in[1];
  const float* W1  = (const float*)d_in[2];
  const float* a   = (const float*)d_in[3];
  const float* W2w = (const float*)d_in[4];
  const float* W2b = (const float*)d_in[5];
  float* out = (float*)d_out;

  char* ws = (char*)d_ws;
  uint16_t* Up   = (uint16_t*)(ws + 0);
  uint16_t* w2bp = (uint16_t*)(ws + 32768);
  uint16_t* stp  = (uint16_t*)(ws + 65536);

  pack_kernel<<<136, 256, 0, stream>>>(W1, W2w, a, Up, w2bp, stp);
  camgat_kernel<<<NTILES, 64*WPG, 0, stream>>>(x, cam, W2b, Up, w2bp, stp, out);
}

// Round 7
// 113.381 us; speedup vs baseline: 1.5696x; 1.5696x over previous
//
#include <hip/hip_runtime.h>
#include <hip/hip_bf16.h>
#include <stdint.h>

#define NJ 21
#define ROWS_TOTAL (16384*21)      /* 344064 */
#define TILE_ROWS 63               /* 3 batches per tile (one WG) */
#define NTILES ((ROWS_TOTAL + TILE_ROWS - 1)/TILE_ROWS)  /* 5462 */
#define WPG 4                      /* 4 waves per WG; each owns 2 x 16 output feats */

typedef __attribute__((ext_vector_type(8))) short short8;
typedef __attribute__((ext_vector_type(4))) float f32x4;

/* wave-local LDS fence (DS ops of one wave complete in order; this drains them) */
#define WAVE_SYNC() asm volatile("s_waitcnt lgkmcnt(0)" ::: "memory")

__device__ __forceinline__ uint16_t f2bf(float f){
  union{float f; uint32_t u;} v; v.f = f;
  uint32_t r = v.u + 0x7FFF + ((v.u>>16)&1);
  return (uint16_t)(r>>16);
}

/* idx<16384:  Up[frag]   = bf16( (W1@W2a)[k][n] )      (U = W1 @ W2_w[0:128])
   idx<32768:  w2bp[frag] = bf16( W2_w[128+k][n] )
   idx<34816:  stp[frag]  = B-tile [ws | wt | 0...]:  n==0 -> (W1@a1)[k], n==1 -> (W1@a2)[k]
   frag layout: buf[(tile*64 + lane)*8 + e] = M[k=32ks+8*(lane>>4)+e][n=16nt+(lane&15)] */
__global__ void pack_kernel(const float* __restrict__ W1, const float* __restrict__ W2,
                            const float* __restrict__ a,
                            uint16_t* __restrict__ Up, uint16_t* __restrict__ w2bp,
                            uint16_t* __restrict__ stp){
  int idx = blockIdx.x*256 + threadIdx.x;       /* 0..34815 */
  if (idx < 32768){
    int which = idx >> 14;
    int sub = idx & 16383;
    int e = sub & 7, lane = (sub>>3)&63, nt = (sub>>9)&7, ks = sub>>12;
    int k = 32*ks + 8*(lane>>4) + e;
    int n = 16*nt + (lane&15);
    if (which==0){
      float acc = 0.f;
      for (int p=0;p<128;++p) acc += W1[k*128+p]*W2[p*128+n];
      Up[sub] = f2bf(acc);
    } else {
      w2bp[sub] = f2bf(W2[(128+k)*128+n]);
    }
  } else if (idx < 34816){
    int sub = idx - 32768;        /* 0..2047 */
    int e = sub & 7, lane = (sub>>3)&63, ks = (sub>>9)&3;
    int k = 32*ks + 8*(lane>>4) + e;
    int l15 = lane & 15;
    float v = 0.f;
    if (l15 == 0){ for (int p=0;p<128;++p) v += W1[k*128+p]*a[p]; }
    else if (l15 == 1){ for (int p=0;p<128;++p) v += W1[k*128+p]*a[128+p]; }
    stp[sub] = f2bf(v);
  }
}

__global__ __launch_bounds__(256,4) void camgat_kernel(
    const float* __restrict__ x, const float* __restrict__ cam,
    const float* __restrict__ bias,
    const uint16_t* __restrict__ Up, const uint16_t* __restrict__ w2bp,
    const uint16_t* __restrict__ stp,
    float* __restrict__ out)
{
  __shared__ uint16_t sXB[64*128];       /* bf16 x-tile [row64][feat128], XOR-swizzled, 16KB */
  __shared__ uint16_t sALPHA[64*64];     /* block-diag alpha, swizzled, 8KB */
  __shared__ uint16_t sUT[WPG][16*64];   /* per-wave u^T slice [feat16][sample64], swizzled, 2KB ea */
  __shared__ float sST[2][64];           /* s,t per row */

  const int tid  = threadIdx.x;
  const int wv   = tid >> 6;
  const int lane = tid & 63;
  const int g = lane >> 4;
  const int l15 = lane & 15;
  const long row_base = (long)blockIdx.x * TILE_ROWS;

  uint16_t* myUT = sUT[wv];

  /* ---- 0: cooperative x -> bf16 LDS tile (each thread: 1 row x 32 cols) ---- */
  {
    int r  = tid >> 2;            /* 0..63 */
    int c0 = (tid & 3) * 32;
    long grow = row_base + r;
    bool valid = (r < TILE_ROWS) && (grow < (long)ROWS_TOTAL);
    const float* xrow = x + (valid ? grow : 0)*128 + c0;
    float4 v[8];
    #pragma unroll
    for (int j=0;j<8;++j){
      if (valid) v[j] = *(const float4*)(xrow + 4*j);
      else       v[j] = make_float4(0.f,0.f,0.f,0.f);
    }
    #pragma unroll
    for (int j=0;j<4;++j){
      uint4 w;
      w.x = (uint32_t)f2bf(v[2*j].x)   | ((uint32_t)f2bf(v[2*j].y)<<16);
      w.y = (uint32_t)f2bf(v[2*j].z)   | ((uint32_t)f2bf(v[2*j].w)<<16);
      w.z = (uint32_t)f2bf(v[2*j+1].x) | ((uint32_t)f2bf(v[2*j+1].y)<<16);
      w.w = (uint32_t)f2bf(v[2*j+1].z) | ((uint32_t)f2bf(v[2*j+1].w)<<16);
      int addr = (r*256 + (c0 + 8*j)*2) ^ ((r&7)<<4);
      *(uint4*)((char*)sXB + addr) = w;
    }
  }
  __syncthreads();

  /* A-fragment read from swizzled x tile: row, bf16-col (8 consecutive) */
  #define LDX(row, kcol) (*(const short8*)((char*)sXB + (((row)*256 + (kcol)*2) ^ (((row)&7)<<4))))

  /* ---- 1: s,t via st-MFMA (redundant per wave) ---- */
  {
    short8 stf[4];
    #pragma unroll
    for (int ks=0;ks<4;++ks)
      stf[ks] = *(const short8*)(stp + (size_t)(ks*64 + lane)*8);
    f32x4 stacc[4];
    { f32x4 z; z[0]=0.f; z[1]=0.f; z[2]=0.f; z[3]=0.f;
      #pragma unroll
      for (int mi=0;mi<4;++mi) stacc[mi]=z; }
    #pragma unroll
    for (int ks=0;ks<4;++ks)
      #pragma unroll
      for (int mi=0;mi<4;++mi){
        short8 afr = LDX(16*mi + l15, 32*ks + 8*g);
        stacc[mi] = __builtin_amdgcn_mfma_f32_16x16x32_bf16(afr, stf[ks], stacc[mi], 0,0,0);
      }
    if (l15 < 2){
      #pragma unroll
      for (int mi=0;mi<4;++mi)
        #pragma unroll
        for (int q=0;q<4;++q)
          sST[l15][16*mi+4*g+q] = stacc[mi][q];   /* same values from all waves: benign */
    }
  }
  WAVE_SYNC();

  /* ---- 2: softmax rows 16wv..16wv+15 -> alpha (disjoint rows incl zero-complement) ---- */
  if (lane < 16){
    int r = 16*wv + lane;
    bool vrow = (r < TILE_ROWS);
    int qq = (r>=42)?2:((r>=21)?1:0);
    int base = vrow ? 21*qq : 64;
    for (int c=0;c<base;++c){
      int addr = (r*128 + c*2) ^ ((r&7)<<4);
      *(uint16_t*)((char*)sALPHA + addr) = 0;
    }
    for (int c=base+21;c<64;++c){
      int addr = (r*128 + c*2) ^ ((r&7)<<4);
      *(uint16_t*)((char*)sALPHA + addr) = 0;
    }
    if (vrow){
      int i = r - base;
      float s_r = sST[0][r];
      float ev[NJ]; float m = -1e30f;
      #pragma unroll
      for (int j=0;j<NJ;++j){
        float e = s_r + sST[1][base+j];
        e = e>0.f ? e : 0.2f*e;
        ev[j]=e; m = fmaxf(m,e);
      }
      float sum=0.f;
      #pragma unroll
      for (int j=0;j<NJ;++j){ float p = __expf(ev[j]-m); ev[j]=p; sum+=p; }
      float inv = 1.f/sum;
      #pragma unroll
      for (int j=0;j<NJ;++j){
        uint16_t ab = f2bf(cam[i*NJ+j]*ev[j]*inv);
        int addr = (r*128 + (base+j)*2) ^ ((r&7)<<4);
        *(uint16_t*)((char*)sALPHA + addr) = ab;
      }
    }
  }
  __syncthreads();   /* alpha + xbf stable, read-only hereafter */

  /* ---- 3: two 16-feature phases per wave (ntile = 2wv+h) ---- */
  #pragma unroll
  for (int h=0; h<2; ++h){
    const int ntile = 2*wv + h;

    /* merged u-GEMM + w2b-GEMM: one x-fragment feeds both accumulators */
    f32x4 uacc[4], oacc[4];
    {
      f32x4 z; z[0]=0.f; z[1]=0.f; z[2]=0.f; z[3]=0.f;
      float b = bias[16*ntile + l15];
      f32x4 bv; bv[0]=b; bv[1]=b; bv[2]=b; bv[3]=b;
      #pragma unroll
      for (int mi=0;mi<4;++mi){ uacc[mi]=z; oacc[mi]=bv; }
    }
    #pragma unroll
    for (int ks=0;ks<4;++ks){
      short8 bfu = *(const short8*)(Up   + (size_t)(((ks*8)+ntile)*64 + lane)*8);
      short8 bfw = *(const short8*)(w2bp + (size_t)(((ks*8)+ntile)*64 + lane)*8);
      #pragma unroll
      for (int mi=0;mi<4;++mi){
        short8 afr = LDX(16*mi + l15, 32*ks + 8*g);
        uacc[mi] = __builtin_amdgcn_mfma_f32_16x16x32_bf16(afr, bfu, uacc[mi], 0,0,0);
        oacc[mi] = __builtin_amdgcn_mfma_f32_16x16x32_bf16(afr, bfw, oacc[mi], 0,0,0);
      }
    }

    /* pack u^T slice -> own LDS: [feat_local=l15][sample], swizzled */
    #pragma unroll
    for (int mi=0;mi<4;++mi){
      uint32_t lo = (uint32_t)f2bf(uacc[mi][0]) | ((uint32_t)f2bf(uacc[mi][1])<<16);
      uint32_t hi = (uint32_t)f2bf(uacc[mi][2]) | ((uint32_t)f2bf(uacc[mi][3])<<16);
      int addr = (l15*128 + (16*mi + 4*g)*2) ^ ((l15&7)<<4);
      uint2 w; w.x=lo; w.y=hi;
      *(uint2*)((char*)myUT + addr) = w;
    }
    WAVE_SYNC();   /* own uT writes visible wave-wide */

    /* oacc += alpha @ u-slice  (M64 N16 K64) */
    #pragma unroll
    for (int ks2=0;ks2<2;++ks2){
      int kb = (32*ks2 + 8*g)*2;
      short8 bfr = *(const short8*)((char*)myUT + ((l15*128 + kb) ^ ((l15&7)<<4)));
      #pragma unroll
      for (int mi=0;mi<4;++mi){
        int i = 16*mi + l15;
        short8 afr = *(const short8*)((char*)sALPHA + ((i*128 + kb) ^ ((i&7)<<4)));
        oacc[mi] = __builtin_amdgcn_mfma_f32_16x16x32_bf16(afr, bfr, oacc[mi], 0,0,0);
      }
    }

    /* ELU + predicated store of this 16-col slice */
    #pragma unroll
    for (int mi=0;mi<4;++mi){
      #pragma unroll
      for (int q=0;q<4;++q){
        int r = 16*mi + 4*g + q;
        long grow = row_base + r;
        if (r < TILE_ROWS && grow < (long)ROWS_TOTAL){
          float v = oacc[mi][q];
          v = v > 0.f ? v : (__expf(v) - 1.f);
          out[grow*128 + 16*ntile + l15] = v;
        }
      }
    }
    /* h=1 pack writes cannot pass h=0 reads (per-wave DS ops are in-order) */
  }
  #undef LDX
}

extern "C" void kernel_launch(void* const* d_in, const int* in_sizes, int n_in,
                              void* d_out, int out_size, void* d_ws, size_t ws_size,
                              hipStream_t stream) {
  const float* x   = (const float*)d_in[0];
  const float* cam = (const float*)d_in[1];
  const float* W1  = (const float*)d_in[2];
  const float* a   = (const float*)d_in[3];
  const float* W2w = (const float*)d_in[4];
  const float* W2b = (const float*)d_in[5];
  float* out = (float*)d_out;

  char* ws = (char*)d_ws;
  uint16_t* Up   = (uint16_t*)(ws + 0);
  uint16_t* w2bp = (uint16_t*)(ws + 32768);
  uint16_t* stp  = (uint16_t*)(ws + 65536);

  pack_kernel<<<136, 256, 0, stream>>>(W1, W2w, a, Up, w2bp, stp);
  camgat_kernel<<<NTILES, 64*WPG, 0, stream>>>(x, cam, W2b, Up, w2bp, stp, out);
}

// Round 8
// 109.931 us; speedup vs baseline: 1.6189x; 1.0314x over previous
//
#include <hip/hip_runtime.h>
#include <hip/hip_bf16.h>
#include <stdint.h>

#define NJ 21
#define ROWS_TOTAL (16384*21)      /* 344064 */
#define TILE_ROWS 63               /* 3 batches per tile (one WG) */
#define NTILES ((ROWS_TOTAL + TILE_ROWS - 1)/TILE_ROWS)  /* 5462 */
#define WPG 4                      /* 4 waves per WG; each owns 2 x 16 output feats */

typedef __attribute__((ext_vector_type(8))) short short8;
typedef __attribute__((ext_vector_type(4))) float f32x4;

/* wave-local LDS fence (one wave's DS ops complete in order; this drains them) */
#define WAVE_SYNC() asm volatile("s_waitcnt lgkmcnt(0)" ::: "memory")

__device__ __forceinline__ uint16_t f2bf(float f){
  union{float f; uint32_t u;} v; v.f = f;
  uint32_t r = v.u + 0x7FFF + ((v.u>>16)&1);
  return (uint16_t)(r>>16);
}

/* idx<16384:  Up[frag]   = bf16( (W1@W2a)[k][n] )      (U = W1 @ W2_w[0:128])
   idx<32768:  w2bp[frag] = bf16( W2_w[128+k][n] )
   idx<34816:  stp[frag]  = B-tile [ws | wt | 0...]:  n==0 -> (W1@a1)[k], n==1 -> (W1@a2)[k]
   frag layout: buf[(tile*64 + lane)*8 + e] = M[k=32ks+8*(lane>>4)+e][n=16nt+(lane&15)] */
__global__ void pack_kernel(const float* __restrict__ W1, const float* __restrict__ W2,
                            const float* __restrict__ a,
                            uint16_t* __restrict__ Up, uint16_t* __restrict__ w2bp,
                            uint16_t* __restrict__ stp){
  int idx = blockIdx.x*256 + threadIdx.x;       /* 0..34815 */
  if (idx < 32768){
    int which = idx >> 14;
    int sub = idx & 16383;
    int e = sub & 7, lane = (sub>>3)&63, nt = (sub>>9)&7, ks = sub>>12;
    int k = 32*ks + 8*(lane>>4) + e;
    int n = 16*nt + (lane&15);
    if (which==0){
      float acc = 0.f;
      for (int p=0;p<128;++p) acc += W1[k*128+p]*W2[p*128+n];
      Up[sub] = f2bf(acc);
    } else {
      w2bp[sub] = f2bf(W2[(128+k)*128+n]);
    }
  } else if (idx < 34816){
    int sub = idx - 32768;        /* 0..2047 */
    int e = sub & 7, lane = (sub>>3)&63, ks = (sub>>9)&3;
    int k = 32*ks + 8*(lane>>4) + e;
    int l15 = lane & 15;
    float v = 0.f;
    if (l15 == 0){ for (int p=0;p<128;++p) v += W1[k*128+p]*a[p]; }
    else if (l15 == 1){ for (int p=0;p<128;++p) v += W1[k*128+p]*a[128+p]; }
    stp[sub] = f2bf(v);
  }
}

__global__ __launch_bounds__(256,4) void camgat_kernel(
    const float* __restrict__ x, const float* __restrict__ cam,
    const float* __restrict__ bias,
    const uint16_t* __restrict__ Up, const uint16_t* __restrict__ w2bp,
    const uint16_t* __restrict__ stp,
    float* __restrict__ out)
{
  __shared__ uint16_t sXB[4*4*64*8];     /* x A-frags, FRAGMENT-LINEAR [mi][ks][lane][e], 16KB */
  __shared__ uint16_t sALPHA[64*64];     /* block-diag alpha, swizzled, 8KB */
  __shared__ uint16_t sUT[WPG][16*64];   /* per-wave u^T slice [feat16][sample64], swizzled, 2KB ea */
  __shared__ float sST[2][64];           /* s,t per row (wave 0 writes) */

  const int tid  = threadIdx.x;
  const int wv   = tid >> 6;
  const int lane = tid & 63;
  const int g = lane >> 4;
  const int l15 = lane & 15;
  const long row_base = (long)blockIdx.x * TILE_ROWS;

  uint16_t* myUT = sUT[wv];

  /* A-fragment read: lane-stride-16B, compile-time base offset -> zero addr math */
  #define LDXF(mi,ks) (*(const short8*)(sXB + (((mi)*4+(ks))*64 + lane)*8))

  /* ---- 0a: cooperative alpha zero (vectorized, swizzle-invariant) ---- */
  {
    uint4 z4; z4.x=0; z4.y=0; z4.z=0; z4.w=0;
    ((uint4*)sALPHA)[tid]       = z4;
    ((uint4*)sALPHA)[tid + 256] = z4;
  }

  /* ---- 0b: cooperative x -> bf16 frags in LDS (thread: 1 row x 32 cols) ---- */
  {
    int r  = tid >> 2;            /* 0..63 */
    int c4 = tid & 3;             /* which 32-col group = ks */
    int smi = r >> 4, sl15 = r & 15;
    long grow = row_base + r;
    bool valid = (r < TILE_ROWS) && (grow < (long)ROWS_TOTAL);
    const float* xrow = x + (valid ? grow : 0)*128 + c4*32;
    float4 v[8];
    #pragma unroll
    for (int j=0;j<8;++j){
      if (valid) v[j] = *(const float4*)(xrow + 4*j);
      else       v[j] = make_float4(0.f,0.f,0.f,0.f);
    }
    #pragma unroll
    for (int j=0;j<4;++j){        /* j = g group of cols c4*32+8j */
      uint4 w;
      w.x = (uint32_t)f2bf(v[2*j].x)   | ((uint32_t)f2bf(v[2*j].y)<<16);
      w.y = (uint32_t)f2bf(v[2*j].z)   | ((uint32_t)f2bf(v[2*j].w)<<16);
      w.z = (uint32_t)f2bf(v[2*j+1].x) | ((uint32_t)f2bf(v[2*j+1].y)<<16);
      w.w = (uint32_t)f2bf(v[2*j+1].z) | ((uint32_t)f2bf(v[2*j+1].w)<<16);
      *(uint4*)(sXB + ((size_t)((smi*4 + c4)*64 + 16*j + sl15))*8) = w;
    }
  }
  __syncthreads();

  /* ---- 1: wave 0 only: s,t via st-MFMA, then softmax for ALL rows ---- */
  if (wv == 0){
    short8 stf[4];
    #pragma unroll
    for (int ks=0;ks<4;++ks)
      stf[ks] = *(const short8*)(stp + (size_t)(ks*64 + lane)*8);
    f32x4 stacc[4];
    { f32x4 z; z[0]=0.f; z[1]=0.f; z[2]=0.f; z[3]=0.f;
      #pragma unroll
      for (int mi=0;mi<4;++mi) stacc[mi]=z; }
    #pragma unroll
    for (int ks=0;ks<4;++ks)
      #pragma unroll
      for (int mi=0;mi<4;++mi)
        stacc[mi] = __builtin_amdgcn_mfma_f32_16x16x32_bf16(LDXF(mi,ks), stf[ks], stacc[mi], 0,0,0);
    /* scatter: C layout col=l15 (0->s, 1->t), row=16mi+4g+q */
    if (l15 < 2){
      #pragma unroll
      for (int mi=0;mi<4;++mi)
        #pragma unroll
        for (int q=0;q<4;++q)
          sST[l15][16*mi+4*g+q] = stacc[mi][q];
    }
    WAVE_SYNC();   /* sST visible wave-wide */

    /* softmax: lane = row (63 active lanes, one pass) */
    if (lane < TILE_ROWS){
      int r = lane;
      int qq = (r>=42)?2:((r>=21)?1:0);
      int i = r - 21*qq, base = 21*qq;
      float s_r = sST[0][r];
      float ev[NJ]; float m = -1e30f;
      #pragma unroll
      for (int j=0;j<NJ;++j){
        float e = s_r + sST[1][base+j];
        e = e>0.f ? e : 0.2f*e;
        ev[j]=e; m = fmaxf(m,e);
      }
      float sum=0.f;
      #pragma unroll
      for (int j=0;j<NJ;++j){ float p = __expf(ev[j]-m); ev[j]=p; sum+=p; }
      float inv = 1.f/sum;
      #pragma unroll
      for (int j=0;j<NJ;++j){
        uint16_t ab = f2bf(cam[i*NJ+j]*ev[j]*inv);
        int addr = (r*128 + (base+j)*2) ^ ((r&7)<<4);
        *(uint16_t*)((char*)sALPHA + addr) = ab;
      }
    }
  }
  __syncthreads();   /* alpha complete; sXB/sALPHA read-only hereafter */

  /* ---- 2: two 16-feature phases per wave (ntile = 2wv+h) ---- */
  #pragma unroll
  for (int h=0; h<2; ++h){
    const int ntile = 2*wv + h;

    /* u-GEMM slice: M64 N16 K128 */
    short8 bfu[4];
    #pragma unroll
    for (int ks=0;ks<4;++ks)
      bfu[ks] = *(const short8*)(Up + (size_t)(((ks*8)+ntile)*64 + lane)*8);
    f32x4 uacc[4];
    { f32x4 z; z[0]=0.f; z[1]=0.f; z[2]=0.f; z[3]=0.f;
      #pragma unroll
      for (int mi=0;mi<4;++mi) uacc[mi]=z; }
    #pragma unroll
    for (int ks=0;ks<4;++ks)
      #pragma unroll
      for (int mi=0;mi<4;++mi)
        uacc[mi] = __builtin_amdgcn_mfma_f32_16x16x32_bf16(LDXF(mi,ks), bfu[ks], uacc[mi], 0,0,0);

    /* pack u^T slice -> own LDS: [feat_local=l15][sample], swizzled */
    #pragma unroll
    for (int mi=0;mi<4;++mi){
      uint32_t lo = (uint32_t)f2bf(uacc[mi][0]) | ((uint32_t)f2bf(uacc[mi][1])<<16);
      uint32_t hi = (uint32_t)f2bf(uacc[mi][2]) | ((uint32_t)f2bf(uacc[mi][3])<<16);
      int addr = (l15*128 + (16*mi + 4*g)*2) ^ ((l15&7)<<4);
      uint2 w; w.x=lo; w.y=hi;
      *(uint2*)((char*)myUT + addr) = w;
    }

    /* w2b-GEMM slice (uT write latency hides under these 16 MFMAs) */
    short8 bfw[4];
    #pragma unroll
    for (int ks=0;ks<4;++ks)
      bfw[ks] = *(const short8*)(w2bp + (size_t)(((ks*8)+ntile)*64 + lane)*8);
    f32x4 oacc[4];
    {
      float b = bias[16*ntile + l15];
      f32x4 bv; bv[0]=b; bv[1]=b; bv[2]=b; bv[3]=b;
      #pragma unroll
      for (int mi=0;mi<4;++mi) oacc[mi]=bv;
    }
    #pragma unroll
    for (int ks=0;ks<4;++ks)
      #pragma unroll
      for (int mi=0;mi<4;++mi)
        oacc[mi] = __builtin_amdgcn_mfma_f32_16x16x32_bf16(LDXF(mi,ks), bfw[ks], oacc[mi], 0,0,0);

    WAVE_SYNC();   /* own uT writes visible */

    /* oacc += alpha @ u-slice  (M64 N16 K64) */
    #pragma unroll
    for (int ks2=0;ks2<2;++ks2){
      int kb = (32*ks2 + 8*g)*2;
      short8 bfr = *(const short8*)((char*)myUT + ((l15*128 + kb) ^ ((l15&7)<<4)));
      #pragma unroll
      for (int mi=0;mi<4;++mi){
        int i = 16*mi + l15;
        short8 afr = *(const short8*)((char*)sALPHA + ((i*128 + kb) ^ ((i&7)<<4)));
        oacc[mi] = __builtin_amdgcn_mfma_f32_16x16x32_bf16(afr, bfr, oacc[mi], 0,0,0);
      }
    }

    /* ELU + predicated store of this 16-col slice */
    #pragma unroll
    for (int mi=0;mi<4;++mi){
      #pragma unroll
      for (int q=0;q<4;++q){
        int r = 16*mi + 4*g + q;
        long grow = row_base + r;
        if (r < TILE_ROWS && grow < (long)ROWS_TOTAL){
          float v = oacc[mi][q];
          v = v > 0.f ? v : (__expf(v) - 1.f);
          out[grow*128 + 16*ntile + l15] = v;
        }
      }
    }
    /* h=1 uT pack cannot pass h=0 uT reads (per-wave DS ops are in-order) */
  }
  #undef LDXF
}

extern "C" void kernel_launch(void* const* d_in, const int* in_sizes, int n_in,
                              void* d_out, int out_size, void* d_ws, size_t ws_size,
                              hipStream_t stream) {
  const float* x   = (const float*)d_in[0];
  const float* cam = (const float*)d_in[1];
  const float* W1  = (const float*)d_in[2];
  const float* a   = (const float*)d_in[3];
  const float* W2w = (const float*)d_in[4];
  const float* W2b = (const float*)d_in[5];
  float* out = (float*)d_out;

  char* ws = (char*)d_ws;
  uint16_t* Up   = (uint16_t*)(ws + 0);
  uint16_t* w2bp = (uint16_t*)(ws + 32768);
  uint16_t* stp  = (uint16_t*)(ws + 65536);

  pack_kernel<<<136, 256, 0, stream>>>(W1, W2w, a, Up, w2bp, stp);
  camgat_kernel<<<NTILES, 64*WPG, 0, stream>>>(x, cam, W2b, Up, w2bp, stp, out);
}

// Round 9
// 91.719 us; speedup vs baseline: 1.9403x; 1.1986x over previous
//
#include <hip/hip_runtime.h>
#include <hip/hip_bf16.h>
#include <stdint.h>

#define NJ 21
#define ROWS_TOTAL (16384*21)      /* 344064 */
#define TILE_ROWS 63               /* 3 batches per tile (one WG) */
#define NTILES ((ROWS_TOTAL + TILE_ROWS - 1)/TILE_ROWS)  /* 5462 */
#define WPG 8                      /* 8 waves per WG; each owns one 16-feat slice */

typedef __attribute__((ext_vector_type(8))) short short8;
typedef __attribute__((ext_vector_type(4))) float f32x4;

/* wave-local LDS fence (one wave's DS ops drained; no WG barrier) */
#define WAVE_SYNC() asm volatile("s_waitcnt lgkmcnt(0)" ::: "memory")

__device__ __forceinline__ uint16_t f2bf(float f){
  union{float f; uint32_t u;} v; v.f = f;
  uint32_t r = v.u + 0x7FFF + ((v.u>>16)&1);
  return (uint16_t)(r>>16);
}

/* idx<16384:  Up[frag]   = bf16( (W1@W2a)[k][n] )      (U = W1 @ W2_w[0:128])
   idx<32768:  w2bp[frag] = bf16( W2_w[128+k][n] )
   idx<34816:  stp[frag]  = B-tile [ws | wt | 0...]:  n==0 -> (W1@a1)[k], n==1 -> (W1@a2)[k]
   frag layout: buf[(tile*64 + lane)*8 + e] = M[k=32ks+8*(lane>>4)+e][n=16nt+(lane&15)] */
__global__ void pack_kernel(const float* __restrict__ W1, const float* __restrict__ W2,
                            const float* __restrict__ a,
                            uint16_t* __restrict__ Up, uint16_t* __restrict__ w2bp,
                            uint16_t* __restrict__ stp){
  int idx = blockIdx.x*256 + threadIdx.x;       /* 0..34815 */
  if (idx < 32768){
    int which = idx >> 14;
    int sub = idx & 16383;
    int e = sub & 7, lane = (sub>>3)&63, nt = (sub>>9)&7, ks = sub>>12;
    int k = 32*ks + 8*(lane>>4) + e;
    int n = 16*nt + (lane&15);
    if (which==0){
      float acc = 0.f;
      for (int p=0;p<128;++p) acc += W1[k*128+p]*W2[p*128+n];
      Up[sub] = f2bf(acc);
    } else {
      w2bp[sub] = f2bf(W2[(128+k)*128+n]);
    }
  } else if (idx < 34816){
    int sub = idx - 32768;        /* 0..2047 */
    int e = sub & 7, lane = (sub>>3)&63, ks = (sub>>9)&3;
    int k = 32*ks + 8*(lane>>4) + e;
    int l15 = lane & 15;
    float v = 0.f;
    if (l15 == 0){ for (int p=0;p<128;++p) v += W1[k*128+p]*a[p]; }
    else if (l15 == 1){ for (int p=0;p<128;++p) v += W1[k*128+p]*a[128+p]; }
    stp[sub] = f2bf(v);
  }
}

__global__ __launch_bounds__(512,8) void camgat_kernel(
    const float* __restrict__ x, const float* __restrict__ cam,
    const float* __restrict__ bias,
    const uint16_t* __restrict__ Up, const uint16_t* __restrict__ w2bp,
    const uint16_t* __restrict__ stp,
    float* __restrict__ out)
{
  __shared__ uint16_t sXB[4*4*64*8];     /* x A-frags, FRAGMENT-LINEAR [mi][ks][slot][e], 16KB */
  __shared__ uint16_t sALPHA[64*64];     /* block-diag alpha, swizzled, 8KB */
  __shared__ uint16_t sUT[WPG][16*64];   /* per-wave u^T slice [feat16][sample64], 2KB each */
  /* sST overlays sUT[0]: used only BEFORE barrier #2; sUT[0] written only after (by wave 0 itself) */
  float* sST = (float*)&sUT[0][0];       /* sST[0..63]=s, sST[64..127]=t */

  const int tid  = threadIdx.x;
  const int wv   = tid >> 6;
  const int lane = tid & 63;
  const int g = lane >> 4;
  const int l15 = lane & 15;
  const int row_base = blockIdx.x * TILE_ROWS;

  uint16_t* myUT = sUT[wv];

  /* A-fragment read: lane-stride-16B, compile-time base offset */
  #define LDXF(mi,ks) (*(const short8*)(sXB + (((mi)*4+(ks))*64 + lane)*8))

  /* ---- 0a: cooperative alpha zero (512 x 16B = 8KB) ---- */
  {
    uint4 z4; z4.x=0; z4.y=0; z4.z=0; z4.w=0;
    ((uint4*)sALPHA)[tid] = z4;
  }

  /* ---- 0b: cooperative x -> bf16 frags (thread: 1 row x 16 cols) ---- */
  {
    int r   = tid >> 3;           /* 0..63 */
    int c16 = (tid & 7) * 16;     /* col group */
    int smi = r >> 4, sl15 = r & 15;
    int ks  = c16 >> 5;
    int g0  = (c16 & 31) >> 3;    /* 0 or 2 */
    long grow = (long)row_base + r;
    bool valid = (r < TILE_ROWS) && (grow < (long)ROWS_TOTAL);
    const float* xrow = x + (valid ? grow : 0)*128 + c16;
    float4 v0 = *(const float4*)(xrow + 0);
    float4 v1 = *(const float4*)(xrow + 4);
    float4 v2 = *(const float4*)(xrow + 8);
    float4 v3 = *(const float4*)(xrow + 12);
    if (!valid){ v0 = make_float4(0.f,0.f,0.f,0.f); v1=v0; v2=v0; v3=v0; }
    uint4 w0, w1;
    w0.x = (uint32_t)f2bf(v0.x) | ((uint32_t)f2bf(v0.y)<<16);
    w0.y = (uint32_t)f2bf(v0.z) | ((uint32_t)f2bf(v0.w)<<16);
    w0.z = (uint32_t)f2bf(v1.x) | ((uint32_t)f2bf(v1.y)<<16);
    w0.w = (uint32_t)f2bf(v1.z) | ((uint32_t)f2bf(v1.w)<<16);
    w1.x = (uint32_t)f2bf(v2.x) | ((uint32_t)f2bf(v2.y)<<16);
    w1.y = (uint32_t)f2bf(v2.z) | ((uint32_t)f2bf(v2.w)<<16);
    w1.z = (uint32_t)f2bf(v3.x) | ((uint32_t)f2bf(v3.y)<<16);
    w1.w = (uint32_t)f2bf(v3.z) | ((uint32_t)f2bf(v3.w)<<16);
    uint16_t* base = sXB + ((size_t)((smi*4 + ks)*64 + 16*g0 + sl15))*8;
    *(uint4*)(base)        = w0;      /* slot 16*g0 + l15 */
    *(uint4*)(base + 128)  = w1;      /* slot 16*(g0+1) + l15 (+256B) */
  }

  /* ---- 0c: prefetch own weight frags pre-barrier (fly during barrier + wave0 work) ---- */
  short8 bfu[4];
  #pragma unroll
  for (int ks=0;ks<4;++ks)
    bfu[ks] = *(const short8*)(Up + (size_t)(((ks*8)+wv)*64 + lane)*8);
  short8 stf[4];
  if (wv == 0){
    #pragma unroll
    for (int ks=0;ks<4;++ks)
      stf[ks] = *(const short8*)(stp + (size_t)(ks*64 + lane)*8);
  }
  __syncthreads();

  /* ---- 1: wave 0 only: s,t via st-MFMA, then softmax for all rows ---- */
  if (wv == 0){
    f32x4 stacc[4];
    { f32x4 z; z[0]=0.f; z[1]=0.f; z[2]=0.f; z[3]=0.f;
      #pragma unroll
      for (int mi=0;mi<4;++mi) stacc[mi]=z; }
    #pragma unroll
    for (int ks=0;ks<4;++ks)
      #pragma unroll
      for (int mi=0;mi<4;++mi)
        stacc[mi] = __builtin_amdgcn_mfma_f32_16x16x32_bf16(LDXF(mi,ks), stf[ks], stacc[mi], 0,0,0);
    /* scatter: C layout col=l15 (0->s, 1->t), row=16mi+4g+q */
    if (l15 < 2){
      #pragma unroll
      for (int mi=0;mi<4;++mi)
        #pragma unroll
        for (int q=0;q<4;++q)
          sST[64*l15 + 16*mi+4*g+q] = stacc[mi][q];
    }
    WAVE_SYNC();   /* sST visible wave-wide */

    if (lane < TILE_ROWS){
      int r = lane;
      int qq = (r>=42)?2:((r>=21)?1:0);
      int i = r - 21*qq, base = 21*qq;
      float s_r = sST[r];
      float ev[NJ]; float m = -1e30f;
      #pragma unroll
      for (int j=0;j<NJ;++j){
        float e = s_r + sST[64 + base+j];
        e = e>0.f ? e : 0.2f*e;
        ev[j]=e; m = fmaxf(m,e);
      }
      float sum=0.f;
      #pragma unroll
      for (int j=0;j<NJ;++j){ float p = __expf(ev[j]-m); ev[j]=p; sum+=p; }
      float inv = 1.f/sum;
      #pragma unroll
      for (int j=0;j<NJ;++j){
        uint16_t ab = f2bf(cam[i*NJ+j]*ev[j]*inv);
        int addr = (r*128 + (base+j)*2) ^ ((r&7)<<4);
        *(uint16_t*)((char*)sALPHA + addr) = ab;
      }
    }
  }
  __syncthreads();   /* alpha complete; sXB/sALPHA read-only hereafter */

  /* ---- 2: this wave's 16-feature slice (ntile = wv) ---- */
  /* u-GEMM slice: M64 N16 K128 */
  f32x4 uacc[4];
  { f32x4 z; z[0]=0.f; z[1]=0.f; z[2]=0.f; z[3]=0.f;
    #pragma unroll
    for (int mi=0;mi<4;++mi) uacc[mi]=z; }
  #pragma unroll
  for (int ks=0;ks<4;++ks)
    #pragma unroll
    for (int mi=0;mi<4;++mi)
      uacc[mi] = __builtin_amdgcn_mfma_f32_16x16x32_bf16(LDXF(mi,ks), bfu[ks], uacc[mi], 0,0,0);

  /* pack u^T slice -> own LDS: [feat_local=l15][sample], swizzled */
  #pragma unroll
  for (int mi=0;mi<4;++mi){
    uint32_t lo = (uint32_t)f2bf(uacc[mi][0]) | ((uint32_t)f2bf(uacc[mi][1])<<16);
    uint32_t hi = (uint32_t)f2bf(uacc[mi][2]) | ((uint32_t)f2bf(uacc[mi][3])<<16);
    int addr = (l15*128 + (16*mi + 4*g)*2) ^ ((l15&7)<<4);
    uint2 w; w.x=lo; w.y=hi;
    *(uint2*)((char*)myUT + addr) = w;
  }

  /* w2b-GEMM slice (hides uT write drain + bfw load latency) */
  short8 bfw[4];
  #pragma unroll
  for (int ks=0;ks<4;++ks)
    bfw[ks] = *(const short8*)(w2bp + (size_t)(((ks*8)+wv)*64 + lane)*8);
  f32x4 oacc[4];
  {
    float b = bias[16*wv + l15];
    f32x4 bv; bv[0]=b; bv[1]=b; bv[2]=b; bv[3]=b;
    #pragma unroll
    for (int mi=0;mi<4;++mi) oacc[mi]=bv;
  }
  #pragma unroll
  for (int ks=0;ks<4;++ks)
    #pragma unroll
    for (int mi=0;mi<4;++mi)
      oacc[mi] = __builtin_amdgcn_mfma_f32_16x16x32_bf16(LDXF(mi,ks), bfw[ks], oacc[mi], 0,0,0);

  WAVE_SYNC();   /* own uT writes visible */

  /* oacc += alpha @ u-slice  (M64 N16 K64) */
  #pragma unroll
  for (int ks2=0;ks2<2;++ks2){
    int kb = (32*ks2 + 8*g)*2;
    short8 bfr = *(const short8*)((char*)myUT + ((l15*128 + kb) ^ ((l15&7)<<4)));
    #pragma unroll
    for (int mi=0;mi<4;++mi){
      int i = 16*mi + l15;
      short8 afr = *(const short8*)((char*)sALPHA + ((i*128 + kb) ^ ((i&7)<<4)));
      oacc[mi] = __builtin_amdgcn_mfma_f32_16x16x32_bf16(afr, bfr, oacc[mi], 0,0,0);
    }
  }

  /* ELU + predicated store of this 16-col slice */
  #pragma unroll
  for (int mi=0;mi<4;++mi){
    #pragma unroll
    for (int q=0;q<4;++q){
      int r = 16*mi + 4*g + q;
      long grow = (long)row_base + r;
      if (r < TILE_ROWS && grow < (long)ROWS_TOTAL){
        float v = oacc[mi][q];
        v = v > 0.f ? v : (__expf(v) - 1.f);
        out[grow*128 + 16*wv + l15] = v;
      }
    }
  }
  #undef LDXF
}

extern "C" void kernel_launch(void* const* d_in, const int* in_sizes, int n_in,
                              void* d_out, int out_size, void* d_ws, size_t ws_size,
                              hipStream_t stream) {
  const float* x   = (const float*)d_in[0];
  const float* cam = (const float*)d_in[1];
  const float* W1  = (const float*)d_in[2];
  const float* a   = (const float*)d_in[3];
  const float* W2w = (const float*)d_in[4];
  const float* W2b = (const float*)d_in[5];
  float* out = (float*)d_out;

  char* ws = (char*)d_ws;
  uint16_t* Up   = (uint16_t*)(ws + 0);
  uint16_t* w2bp = (uint16_t*)(ws + 32768);
  uint16_t* stp  = (uint16_t*)(ws + 65536);

  pack_kernel<<<136, 256, 0, stream>>>(W1, W2w, a, Up, w2bp, stp);
  camgat_kernel<<<NTILES, 64*WPG, 0, stream>>>(x, cam, W2b, Up, w2bp, stp, out);
}